// Round 4
// baseline (141.712 us; speedup 1.0000x reference)
//
#include <hip/hip_runtime.h>

#define SDIM 4096
#define DDIM 64
#define HN   16
#define BH   64
#define NC   16

// ---------------------------------------------------------------------------
// k1: per (bh, chunk of 256 rows) partial KV[64][64] + partial ksum[64].
// 64-row LDS tiles (32 KB) -> 4 blocks/CU co-resident (barrier overlap).
// ---------------------------------------------------------------------------
__global__ __launch_bounds__(256) void k1_kv(
    const float* __restrict__ K, const float* __restrict__ V,
    const int* __restrict__ mask,
    float* __restrict__ KVp, float* __restrict__ ksump)
{
    __shared__ float lds[8192];            // 32 KB: Ks[64][64] | Vs[64][64]
    float* Ks = lds;
    float* Vs = lds + 4096;

    const int bh = blockIdx.x / NC;
    const int ch = blockIdx.x % NC;
    const int b  = bh / HN;
    const int tid  = threadIdx.x;
    const int wave = tid >> 6;
    const int lane = tid & 63;
    const int di = lane >> 3;              // 0..7 (d sub-block)
    const int ej = lane & 7;               // 0..7 (e sub-block)
    const long base = (long)bh * SDIM * DDIM;
    const int s0 = ch * (SDIM / NC);       // 256 rows per block

    float acc[8][8];
#pragma unroll
    for (int i = 0; i < 8; ++i)
#pragma unroll
        for (int j = 0; j < 8; ++j) acc[i][j] = 0.f;
    float ksacc[8];
#pragma unroll
    for (int i = 0; i < 8; ++i) ksacc[i] = 0.f;

    for (int t = 0; t < 4; ++t) {          // 4 tiles of 64 rows
        const int r0 = s0 + t * 64;
        __syncthreads();
#pragma unroll
        for (int i = 0; i < 4; ++i) {
            const int f  = tid + i * 256;      // float4 index 0..1023
            const int r  = f >> 4;             // row 0..63
            const int c4 = (f & 15) << 2;      // col
            const int sg = r0 + r;
            float4 kq = *(const float4*)(K + base + (long)sg * DDIM + c4);
            const float mv = mask[b * SDIM + sg] ? 1.f : 0.f;
            kq.x = fmaxf(kq.x, 0.f) * mv;
            kq.y = fmaxf(kq.y, 0.f) * mv;
            kq.z = fmaxf(kq.z, 0.f) * mv;
            kq.w = fmaxf(kq.w, 0.f) * mv;
            *(float4*)(Ks + r * 64 + c4) = kq;
            *(float4*)(Vs + r * 64 + c4) =
                *(const float4*)(V + base + (long)sg * DDIM + c4);
        }
        __syncthreads();
        const int rb = wave * 16;              // each wave owns 16 rows
#pragma unroll 2
        for (int s = 0; s < 16; ++s) {
            float kf[8], vf[8];
            *(float4*)(kf)     = *(const float4*)(Ks + (rb + s) * 64 + di * 8);
            *(float4*)(kf + 4) = *(const float4*)(Ks + (rb + s) * 64 + di * 8 + 4);
            *(float4*)(vf)     = *(const float4*)(Vs + (rb + s) * 64 + ej * 8);
            *(float4*)(vf + 4) = *(const float4*)(Vs + (rb + s) * 64 + ej * 8 + 4);
#pragma unroll
            for (int i = 0; i < 8; ++i)
#pragma unroll
                for (int j = 0; j < 8; ++j)
                    acc[i][j] = fmaf(kf[i], vf[j], acc[i][j]);
            if (ej == 0) {
#pragma unroll
                for (int i = 0; i < 8; ++i) ksacc[i] += kf[i];
            }
        }
    }

    // cross-wave reduce in two 2048-float halves (fits 8192-float LDS)
    __syncthreads();
    float* outp = KVp + ((long)bh * NC + ch) * 4096;
#pragma unroll
    for (int h = 0; h < 2; ++h) {
        if ((di >> 2) == h) {
#pragma unroll
            for (int i = 0; i < 8; ++i)
#pragma unroll
                for (int j = 0; j < 8; j += 4)
                    *(float4*)(&lds[wave * 2048 + ((di & 3) * 8 + i) * 64 +
                                    ej * 8 + j]) = *(float4*)(&acc[i][j]);
        }
        __syncthreads();
#pragma unroll
        for (int i = 0; i < 8; ++i) {
            const int idx = i * 256 + tid;
            outp[h * 2048 + idx] =
                lds[idx] + lds[2048 + idx] + lds[4096 + idx] + lds[6144 + idx];
        }
        __syncthreads();
    }
    // ksum cross-wave reduce
    if (ej == 0) {
#pragma unroll
        for (int i = 0; i < 8; ++i) lds[wave * 64 + di * 8 + i] = ksacc[i];
    }
    __syncthreads();
    if (tid < 64) {
        ksump[((long)bh * NC + ch) * 64 + tid] =
            lds[tid] + lds[64 + tid] + lds[128 + tid] + lds[192 + tid];
    }
}

// ---------------------------------------------------------------------------
// k2: reduce NC chunk partials -> final KV, ksum. 256 blocks (4 per bh).
// ---------------------------------------------------------------------------
__global__ __launch_bounds__(256) void k2_reduce(
    const float* __restrict__ KVp, const float* __restrict__ ksump,
    float* __restrict__ KV, float* __restrict__ ksum)
{
    const int bh = blockIdx.x >> 2;
    const int qt = blockIdx.x & 3;
    const int tid = threadIdx.x;
#pragma unroll
    for (int i = 0; i < 4; ++i) {
        const int idx = qt * 1024 + i * 256 + tid;
        float v = 0.f;
#pragma unroll
        for (int c = 0; c < NC; ++c) v += KVp[((long)bh * NC + c) * 4096 + idx];
        KV[(long)bh * 4096 + idx] = v;
    }
    if (qt == 0 && tid < 64) {
        float v = 0.f;
#pragma unroll
        for (int c = 0; c < NC; ++c) v += ksump[((long)bh * NC + c) * 64 + tid];
        ksum[bh * 64 + tid] = v;
    }
}

// ---------------------------------------------------------------------------
// k3 v3: one wave per block, 64 rows x 64 cols, per-lane 8x8 outer product.
//  - Q staged in 16 KB wave-private LDS, XOR-swizzled (conflict-free b128
//    both directions), NORM PRE-DIVIDED into Q at staging (no epilogue).
//  - KV read directly from global (16 KB/bh, L1/L2-resident) -> LDS pipe
//    carries only Q: 128 ds_read_b128 per wave for 4096 FMA issues.
// ---------------------------------------------------------------------------
__global__ __launch_bounds__(64, 3) void k3_out(
    const float* __restrict__ Q, const float* __restrict__ KVm,
    const float* __restrict__ ksum, float* __restrict__ out)
{
    __shared__ float qbuf[4096];           // 16 KB
    const int tid = threadIdx.x;           // one wave
    const int bh    = blockIdx.x >> 6;
    const int strip = blockIdx.x & 63;     // 64 strips x 64 rows
    const int row0  = strip * 64;
    const int si = tid >> 3;               // 0..7 row sub-block
    const int ej = tid & 7;                // 0..7 col sub-block

    // ---- stage Q: load 64x64, relu, per-row norm, pre-divide, swizzle-store
    const float* qp = Q + ((long)bh * SDIM + row0) * DDIM;
    const float4 ks4 = *(const float4*)(ksum + bh * 64 + (tid & 15) * 4);

    float4 A[16];
#pragma unroll
    for (int k = 0; k < 16; ++k)
        A[k] = *(const float4*)(qp + (tid + k * 64) * 4);
#pragma unroll
    for (int k = 0; k < 16; ++k) {
        A[k].x = fmaxf(A[k].x, 0.f); A[k].y = fmaxf(A[k].y, 0.f);
        A[k].z = fmaxf(A[k].z, 0.f); A[k].w = fmaxf(A[k].w, 0.f);
    }
    float p[16];
#pragma unroll
    for (int k = 0; k < 16; ++k)
        p[k] = A[k].x * ks4.x + A[k].y * ks4.y + A[k].z * ks4.z + A[k].w * ks4.w;
    // 16-lane-group allreduce (row = 16 consecutive lanes), 16 chains pipelined
#pragma unroll
    for (int off = 1; off <= 8; off <<= 1) {
#pragma unroll
        for (int k = 0; k < 16; ++k) p[k] += __shfl_xor(p[k], off);
    }
#pragma unroll
    for (int k = 0; k < 16; ++k) {
        const float inv = __builtin_amdgcn_rcpf(p[k]);
        A[k].x *= inv; A[k].y *= inv; A[k].z *= inv; A[k].w *= inv;
        const int r  = (tid >> 4) + 4 * k;     // row 0..63
        const int db = tid & 15;               // d-block 0..15
        *(float4*)(qbuf + r * 64 + ((db ^ (r >> 3)) << 2)) = A[k];
    }
    // wave-private LDS + in-order DS pipe: no barrier needed

    // ---- main: acc[8][8] over 16 d-quads; kv from global, q from LDS
    float acc[8][8];
#pragma unroll
    for (int i = 0; i < 8; ++i)
#pragma unroll
        for (int j = 0; j < 8; ++j) acc[i][j] = 0.f;

    const float* kvp = KVm + (long)bh * 4096 + ej * 8;
#pragma unroll
    for (int dq = 0; dq < 16; ++dq) {
        float kvr[4][8];
#pragma unroll
        for (int j = 0; j < 4; ++j) {
            *(float4*)(&kvr[j][0]) = *(const float4*)(kvp + (dq * 4 + j) * 64);
            *(float4*)(&kvr[j][4]) = *(const float4*)(kvp + (dq * 4 + j) * 64 + 4);
        }
#pragma unroll
        for (int r = 0; r < 8; ++r) {
            const int s = si * 8 + r;
            float4 qv = *(const float4*)(qbuf + s * 64 + ((dq ^ si) << 2));
            float qf[4] = {qv.x, qv.y, qv.z, qv.w};
#pragma unroll
            for (int j = 0; j < 4; ++j)
#pragma unroll
                for (int c = 0; c < 8; ++c)
                    acc[r][c] = fmaf(qf[j], kvr[j][c], acc[r][c]);
        }
    }

    // ---- store (already divided): coalesced b128
    float* ob = out + ((long)bh * SDIM + row0) * DDIM;
#pragma unroll
    for (int r = 0; r < 8; ++r) {
        const int s = si * 8 + r;
        *(float4*)(ob + s * 64 + ej * 8)     = *(float4*)(&acc[r][0]);
        *(float4*)(ob + s * 64 + ej * 8 + 4) = *(float4*)(&acc[r][4]);
    }
}

extern "C" void kernel_launch(void* const* d_in, const int* in_sizes, int n_in,
                              void* d_out, int out_size, void* d_ws, size_t ws_size,
                              hipStream_t stream)
{
    const float* Q    = (const float*)d_in[0];
    const float* K    = (const float*)d_in[1];
    const float* V    = (const float*)d_in[2];
    const int*   mask = (const int*)d_in[3];
    float* out = (float*)d_out;

    // Chunk partials live in d_out (scratch; k3 overwrites all of d_out).
    float* KVp   = out;                                // 64*16*4096 f32 = 16.8 MB
    float* ksump = KVp + (long)BH * NC * 4096;         // 256 KB
    float* KV    = (float*)d_ws;                       // 1 MB
    float* ksum  = KV + (long)BH * 4096;               // 16 KB

    hipLaunchKernelGGL(k1_kv, dim3(BH * NC), dim3(256), 0, stream,
                       K, V, mask, KVp, ksump);
    hipLaunchKernelGGL(k2_reduce, dim3(BH * 4), dim3(256), 0, stream,
                       KVp, ksump, KV, ksum);
    hipLaunchKernelGGL(k3_out, dim3(BH * 64), dim3(64), 0, stream,
                       Q, KV, ksum, out);
}

// Round 5
// 79.134 us; speedup vs baseline: 1.7908x; 1.7908x over previous
//
#include <hip/hip_runtime.h>

#define SDIM 4096
#define DDIM 64
#define HN   16
#define BH   64
#define NC   16

typedef __attribute__((ext_vector_type(8))) short short8;
typedef __attribute__((ext_vector_type(4))) float f32x4;

static __device__ __forceinline__ unsigned short f2bf(float f) {
    unsigned u = __float_as_uint(f);
    return (unsigned short)((u + 0x7FFFu + ((u >> 16) & 1u)) >> 16);   // RNE
}

// ---------------------------------------------------------------------------
// k1: per (bh, chunk of 256 rows) partial KV[64][64] + partial ksum[64].
// (unchanged from round 4)
// ---------------------------------------------------------------------------
__global__ __launch_bounds__(256) void k1_kv(
    const float* __restrict__ K, const float* __restrict__ V,
    const int* __restrict__ mask,
    float* __restrict__ KVp, float* __restrict__ ksump)
{
    __shared__ float lds[8192];            // 32 KB: Ks[64][64] | Vs[64][64]
    float* Ks = lds;
    float* Vs = lds + 4096;

    const int bh = blockIdx.x / NC;
    const int ch = blockIdx.x % NC;
    const int b  = bh / HN;
    const int tid  = threadIdx.x;
    const int wave = tid >> 6;
    const int lane = tid & 63;
    const int di = lane >> 3;
    const int ej = lane & 7;
    const long base = (long)bh * SDIM * DDIM;
    const int s0 = ch * (SDIM / NC);       // 256 rows per block

    float acc[8][8];
#pragma unroll
    for (int i = 0; i < 8; ++i)
#pragma unroll
        for (int j = 0; j < 8; ++j) acc[i][j] = 0.f;
    float ksacc[8];
#pragma unroll
    for (int i = 0; i < 8; ++i) ksacc[i] = 0.f;

    for (int t = 0; t < 4; ++t) {          // 4 tiles of 64 rows
        const int r0 = s0 + t * 64;
        __syncthreads();
#pragma unroll
        for (int i = 0; i < 4; ++i) {
            const int f  = tid + i * 256;
            const int r  = f >> 4;
            const int c4 = (f & 15) << 2;
            const int sg = r0 + r;
            float4 kq = *(const float4*)(K + base + (long)sg * DDIM + c4);
            const float mv = mask[b * SDIM + sg] ? 1.f : 0.f;
            kq.x = fmaxf(kq.x, 0.f) * mv;
            kq.y = fmaxf(kq.y, 0.f) * mv;
            kq.z = fmaxf(kq.z, 0.f) * mv;
            kq.w = fmaxf(kq.w, 0.f) * mv;
            *(float4*)(Ks + r * 64 + c4) = kq;
            *(float4*)(Vs + r * 64 + c4) =
                *(const float4*)(V + base + (long)sg * DDIM + c4);
        }
        __syncthreads();
        const int rb = wave * 16;
#pragma unroll 2
        for (int s = 0; s < 16; ++s) {
            float kf[8], vf[8];
            *(float4*)(kf)     = *(const float4*)(Ks + (rb + s) * 64 + di * 8);
            *(float4*)(kf + 4) = *(const float4*)(Ks + (rb + s) * 64 + di * 8 + 4);
            *(float4*)(vf)     = *(const float4*)(Vs + (rb + s) * 64 + ej * 8);
            *(float4*)(vf + 4) = *(const float4*)(Vs + (rb + s) * 64 + ej * 8 + 4);
#pragma unroll
            for (int i = 0; i < 8; ++i)
#pragma unroll
                for (int j = 0; j < 8; ++j)
                    acc[i][j] = fmaf(kf[i], vf[j], acc[i][j]);
            if (ej == 0) {
#pragma unroll
                for (int i = 0; i < 8; ++i) ksacc[i] += kf[i];
            }
        }
    }

    __syncthreads();
    float* outp = KVp + ((long)bh * NC + ch) * 4096;
#pragma unroll
    for (int h = 0; h < 2; ++h) {
        if ((di >> 2) == h) {
#pragma unroll
            for (int i = 0; i < 8; ++i)
#pragma unroll
                for (int j = 0; j < 8; j += 4)
                    *(float4*)(&lds[wave * 2048 + ((di & 3) * 8 + i) * 64 +
                                    ej * 8 + j]) = *(float4*)(&acc[i][j]);
        }
        __syncthreads();
#pragma unroll
        for (int i = 0; i < 8; ++i) {
            const int idx = i * 256 + tid;
            outp[h * 2048 + idx] =
                lds[idx] + lds[2048 + idx] + lds[4096 + idx] + lds[6144 + idx];
        }
        __syncthreads();
    }
    if (ej == 0) {
#pragma unroll
        for (int i = 0; i < 8; ++i) lds[wave * 64 + di * 8 + i] = ksacc[i];
    }
    __syncthreads();
    if (tid < 64) {
        ksump[((long)bh * NC + ch) * 64 + tid] =
            lds[tid] + lds[64 + tid] + lds[128 + tid] + lds[192 + tid];
    }
}

// ---------------------------------------------------------------------------
// k2: reduce NC chunk partials -> final KV, ksum. (unchanged)
// ---------------------------------------------------------------------------
__global__ __launch_bounds__(256) void k2_reduce(
    const float* __restrict__ KVp, const float* __restrict__ ksump,
    float* __restrict__ KV, float* __restrict__ ksum)
{
    const int bh = blockIdx.x >> 2;
    const int qt = blockIdx.x & 3;
    const int tid = threadIdx.x;
#pragma unroll
    for (int i = 0; i < 4; ++i) {
        const int idx = qt * 1024 + i * 256 + tid;
        float v = 0.f;
#pragma unroll
        for (int c = 0; c < NC; ++c) v += KVp[((long)bh * NC + c) * 4096 + idx];
        KV[(long)bh * 4096 + idx] = v;
    }
    if (qt == 0 && tid < 64) {
        float v = 0.f;
#pragma unroll
        for (int c = 0; c < NC; ++c) v += ksump[((long)bh * NC + c) * 64 + tid];
        ksum[bh * 64 + tid] = v;
    }
}

// ---------------------------------------------------------------------------
// k3 v4 (MFMA): out = (relu(Q) @ KV_bf16) * (1/norm), norm in fp32.
//  - A-fragments built straight from coalesced global Q loads (no LDS/bcast).
//  - B (KV, bf16) gathered once per block into VGPRs, L2-resident.
//  - C re-shaped through a wave-private LDS strip (pitch 68) so every global
//    store is a 4x256B-contiguous dwordx4 (avoids the 1.7x write amplification
//    measured in round 4 with 128B-segmented stores).
//  - per lane: r16 = l&15 (A row / B col), quad = l>>4 (k-group).
// ---------------------------------------------------------------------------
__global__ __launch_bounds__(256, 4) void k3_out(
    const float* __restrict__ Q, const float* __restrict__ KVm,
    const float* __restrict__ ksum, float* __restrict__ out)
{
    __shared__ float cbuf[4][16 * 68];     // 17.4 KB, per-wave strips
    const int tid  = threadIdx.x;
    const int w    = tid >> 6;
    const int l    = tid & 63;
    const int r16  = l & 15;
    const int quad = l >> 4;
    const int bh    = blockIdx.x >> 4;
    const int strip = blockIdx.x & 15;     // 16 strips x 256 rows

    // ---- B fragments: KV -> bf16, gathered once (KV total 1 MB, L2-hot)
    const float* kvp = KVm + (long)bh * 4096;
    short8 bfrag[2][4];
#pragma unroll
    for (int kh = 0; kh < 2; ++kh)
#pragma unroll
        for (int n = 0; n < 4; ++n) {
            short8 tmp;
#pragma unroll
            for (int j = 0; j < 8; ++j)
                tmp[j] = (short)f2bf(kvp[(kh * 32 + quad * 8 + j) * 64 + n * 16 + r16]);
            bfrag[kh][n] = tmp;
        }
    float ksv[16];
#pragma unroll
    for (int j = 0; j < 8; ++j) {
        ksv[j]     = ksum[bh * 64 + quad * 8 + j];
        ksv[j + 8] = ksum[bh * 64 + 32 + quad * 8 + j];
    }

    const int rowbase = strip * 256 + w * 64;
    const float* qptr = Q + ((long)bh * SDIM + rowbase + r16) * DDIM + quad * 8;
    float* obase = out + ((long)bh * SDIM + rowbase) * DDIM;
    float* cw = &cbuf[w][0];

    // prefetch tile 0
    f32x4 a0 = *(const f32x4*)(qptr);
    f32x4 a1 = *(const f32x4*)(qptr + 4);
    f32x4 a2 = *(const f32x4*)(qptr + 32);
    f32x4 a3 = *(const f32x4*)(qptr + 36);

    for (int t = 0; t < 4; ++t) {          // 4 tiles of 16 rows per wave
        f32x4 b0 = a0, b1 = a1, b2 = a2, b3 = a3;
        if (t < 3) {                        // prefetch next tile's A
            const float* qn = qptr + (t + 1) * 16 * DDIM;
            b0 = *(const f32x4*)(qn);
            b1 = *(const f32x4*)(qn + 4);
            b2 = *(const f32x4*)(qn + 32);
            b3 = *(const f32x4*)(qn + 36);
        }
        // relu (fp32)
#pragma unroll
        for (int j = 0; j < 4; ++j) {
            a0[j] = fmaxf(a0[j], 0.f); a1[j] = fmaxf(a1[j], 0.f);
            a2[j] = fmaxf(a2[j], 0.f); a3[j] = fmaxf(a3[j], 0.f);
        }
        // norm (fp32): partial over this lane's 16 k's, reduce over k-quads
        float p = 0.f;
#pragma unroll
        for (int j = 0; j < 4; ++j) {
            p = fmaf(a0[j], ksv[j],      p);
            p = fmaf(a1[j], ksv[4 + j],  p);
            p = fmaf(a2[j], ksv[8 + j],  p);
            p = fmaf(a3[j], ksv[12 + j], p);
        }
        p += __shfl_xor(p, 16);
        p += __shfl_xor(p, 32);
        const float inv = __builtin_amdgcn_rcpf(p);  // norm of row r16

        // cvt A to bf16 fragments
        short8 af0, af1;
#pragma unroll
        for (int j = 0; j < 4; ++j) {
            af0[j]     = (short)f2bf(a0[j]);
            af0[4 + j] = (short)f2bf(a1[j]);
            af1[j]     = (short)f2bf(a2[j]);
            af1[4 + j] = (short)f2bf(a3[j]);
        }

        // MFMA: 16 rows x 64 cols, K=64
        f32x4 acc[4];
#pragma unroll
        for (int n = 0; n < 4; ++n) {
            acc[n] = (f32x4){0.f, 0.f, 0.f, 0.f};
            acc[n] = __builtin_amdgcn_mfma_f32_16x16x32_bf16(af0, bfrag[0][n], acc[n], 0, 0, 0);
            acc[n] = __builtin_amdgcn_mfma_f32_16x16x32_bf16(af1, bfrag[1][n], acc[n], 0, 0, 0);
        }

        // fetch 1/norm for the rows this lane's C regs cover (row=(quad*4+r))
        float invr[4];
#pragma unroll
        for (int r = 0; r < 4; ++r) invr[r] = __shfl(inv, quad * 4 + r);

        // C -> LDS (pitch 68: 16B-aligned rows, 2-way-free b32 writes)
#pragma unroll
        for (int n = 0; n < 4; ++n)
#pragma unroll
            for (int r = 0; r < 4; ++r)
                cw[(quad * 4 + r) * 68 + n * 16 + r16] = acc[n][r] * invr[r];

        // LDS -> global: 4 instrs, each 4 rows x 256B fully contiguous
        float* ot = obase + (t * 16) * DDIM;
#pragma unroll
        for (int i = 0; i < 4; ++i) {
            f32x4 v = *(const f32x4*)(cw + (i * 4 + quad) * 68 + r16 * 4);
            *(f32x4*)(ot + (i * 4 + quad) * DDIM + r16 * 4) = v;
        }
        a0 = b0; a1 = b1; a2 = b2; a3 = b3;
    }
}

extern "C" void kernel_launch(void* const* d_in, const int* in_sizes, int n_in,
                              void* d_out, int out_size, void* d_ws, size_t ws_size,
                              hipStream_t stream)
{
    const float* Q    = (const float*)d_in[0];
    const float* K    = (const float*)d_in[1];
    const float* V    = (const float*)d_in[2];
    const int*   mask = (const int*)d_in[3];
    float* out = (float*)d_out;

    // Chunk partials live in d_out (scratch; k3 overwrites all of d_out).
    float* KVp   = out;                                // 16.8 MB scratch
    float* ksump = KVp + (long)BH * NC * 4096;         // 256 KB
    float* KV    = (float*)d_ws;                       // 1 MB
    float* ksum  = KV + (long)BH * 4096;               // 16 KB

    hipLaunchKernelGGL(k1_kv, dim3(BH * NC), dim3(256), 0, stream,
                       K, V, mask, KVp, ksump);
    hipLaunchKernelGGL(k2_reduce, dim3(BH * 4), dim3(256), 0, stream,
                       KVp, ksump, KV, ksum);
    hipLaunchKernelGGL(k3_out, dim3(BH * 16), dim3(256), 0, stream,
                       Q, KV, ksum, out);
}

// Round 6
// 59.400 us; speedup vs baseline: 2.3857x; 1.3322x over previous
//
#include <hip/hip_runtime.h>

#define SDIM 4096
#define DDIM 64
#define HN   16
#define BH   64
#define NC   16

typedef __attribute__((ext_vector_type(8))) short short8;
typedef __attribute__((ext_vector_type(4))) float f32x4;

static __device__ __forceinline__ unsigned short f2bf(float f) {
    unsigned u = __float_as_uint(f);
    return (unsigned short)((u + 0x7FFFu + ((u >> 16) & 1u)) >> 16);   // RNE
}

// ---------------------------------------------------------------------------
// k1 v2 (MFMA): per (bh, chunk of 256 s-rows) partial KV[64][64] + ksum[64].
//  - KV = K^T V as mfma_f32_16x16x32_bf16; each wave owns 64 s-rows.
//  - Fragments gathered DIRECTLY from global: lane reads 8 consecutive s at
//    fixed d -> each instr = 4 full 64B lines, every line consumed once
//    (no overfetch; ~3.4us of L1 traffic hidden under the 21us HBM stream).
//  - relu+mask on K applied per-lane before bf16 cvt (fp32).
//  - ksum[d] = extra MFMA with all-ones B fragment.
//  - cross-wave reduce via pitch-68 LDS (2-way bank aliasing = free).
// ---------------------------------------------------------------------------
__global__ __launch_bounds__(256) void k1_kv(
    const float* __restrict__ K, const float* __restrict__ V,
    const int* __restrict__ mask,
    float* __restrict__ KVp, float* __restrict__ ksump)
{
    __shared__ float red[4 * 2176];        // 34.8 KB
    const int tid  = threadIdx.x;
    const int w    = tid >> 6;
    const int l    = tid & 63;
    const int r16  = l & 15;
    const int quad = l >> 4;
    const int bh = blockIdx.x / NC;
    const int ch = blockIdx.x % NC;
    const int b  = bh / HN;
    const long base = (long)bh * SDIM * DDIM;
    const int s0 = ch * (SDIM / NC) + w * 64;   // this wave's 64 s-rows

    // mask values for this lane's 8 s-rows per k-half (broadcast loads, L1)
    const int* mrow = mask + b * SDIM + s0 + quad * 8;
    float mv[2][8];
#pragma unroll
    for (int kh = 0; kh < 2; ++kh)
#pragma unroll
        for (int j = 0; j < 8; ++j)
            mv[kh][j] = mrow[kh * 32 + j] ? 1.f : 0.f;

    // A fragments from K (relu+mask, bf16), B fragments from V (bf16)
    const float* kp = K + base + (long)(s0 + quad * 8) * DDIM + r16;
    const float* vp = V + base + (long)(s0 + quad * 8) * DDIM + r16;
    short8 afrag[2][4], bfrag[2][4];       // [kh][tile]
#pragma unroll
    for (int kh = 0; kh < 2; ++kh)
#pragma unroll
        for (int dt = 0; dt < 4; ++dt) {
            short8 ta, tb;
#pragma unroll
            for (int j = 0; j < 8; ++j) {
                float kv = kp[(kh * 32 + j) * DDIM + dt * 16];
                kv = fmaxf(kv, 0.f) * mv[kh][j];
                ta[j] = (short)f2bf(kv);
                tb[j] = (short)f2bf(vp[(kh * 32 + j) * DDIM + dt * 16]);
            }
            afrag[kh][dt] = ta;
            bfrag[kh][dt] = tb;
        }

    // MFMA accumulate: acc[dt][et] = 16x16 tile of KV, kacc[dt] = ksum rows
    f32x4 acc[4][4];
#pragma unroll
    for (int i = 0; i < 4; ++i)
#pragma unroll
        for (int j = 0; j < 4; ++j) acc[i][j] = (f32x4){0.f, 0.f, 0.f, 0.f};
    f32x4 kacc[4];
#pragma unroll
    for (int i = 0; i < 4; ++i) kacc[i] = (f32x4){0.f, 0.f, 0.f, 0.f};
    short8 ones;
#pragma unroll
    for (int j = 0; j < 8; ++j) ones[j] = (short)0x3F80;   // bf16 1.0

#pragma unroll
    for (int kh = 0; kh < 2; ++kh) {
#pragma unroll
        for (int dt = 0; dt < 4; ++dt) {
#pragma unroll
            for (int et = 0; et < 4; ++et)
                acc[dt][et] = __builtin_amdgcn_mfma_f32_16x16x32_bf16(
                    afrag[kh][dt], bfrag[kh][et], acc[dt][et], 0, 0, 0);
            kacc[dt] = __builtin_amdgcn_mfma_f32_16x16x32_bf16(
                afrag[kh][dt], ones, kacc[dt], 0, 0, 0);
        }
    }

    // cross-wave reduce: two halves of 32 d-rows (pitch 68 -> 2-way, free)
    float* outp = KVp + ((long)bh * NC + ch) * 4096;
#pragma unroll
    for (int h = 0; h < 2; ++h) {
        __syncthreads();
#pragma unroll
        for (int dt = 0; dt < 2; ++dt)
#pragma unroll
            for (int et = 0; et < 4; ++et)
#pragma unroll
                for (int r = 0; r < 4; ++r)
                    red[w * 2176 + (dt * 16 + quad * 4 + r) * 68 +
                        et * 16 + r16] = acc[h * 2 + dt][et][r];
        __syncthreads();
#pragma unroll
        for (int i = 0; i < 8; ++i) {
            const int idx = i * 256 + tid;
            const int d = idx >> 6, e = idx & 63;
            outp[h * 2048 + idx] =
                red[d * 68 + e] + red[2176 + d * 68 + e] +
                red[4352 + d * 68 + e] + red[6528 + d * 68 + e];
        }
    }
    // ksum reduce (every lane holds the row value; col-redundant)
    __syncthreads();
    if (r16 == 0) {
#pragma unroll
        for (int dt = 0; dt < 4; ++dt)
#pragma unroll
            for (int r = 0; r < 4; ++r)
                red[w * 64 + dt * 16 + quad * 4 + r] = kacc[dt][r];
    }
    __syncthreads();
    if (tid < 64) {
        ksump[((long)bh * NC + ch) * 64 + tid] =
            red[tid] + red[64 + tid] + red[128 + tid] + red[192 + tid];
    }
}

// ---------------------------------------------------------------------------
// k2: reduce NC chunk partials -> final KV, ksum. (unchanged)
// ---------------------------------------------------------------------------
__global__ __launch_bounds__(256) void k2_reduce(
    const float* __restrict__ KVp, const float* __restrict__ ksump,
    float* __restrict__ KV, float* __restrict__ ksum)
{
    const int bh = blockIdx.x >> 2;
    const int qt = blockIdx.x & 3;
    const int tid = threadIdx.x;
#pragma unroll
    for (int i = 0; i < 4; ++i) {
        const int idx = qt * 1024 + i * 256 + tid;
        float v = 0.f;
#pragma unroll
        for (int c = 0; c < NC; ++c) v += KVp[((long)bh * NC + c) * 4096 + idx];
        KV[(long)bh * 4096 + idx] = v;
    }
    if (qt == 0 && tid < 64) {
        float v = 0.f;
#pragma unroll
        for (int c = 0; c < NC; ++c) v += ksump[((long)bh * NC + c) * 64 + tid];
        ksum[bh * 64 + tid] = v;
    }
}

// ---------------------------------------------------------------------------
// k3 v4 (MFMA): out = (relu(Q) @ KV_bf16) * (1/norm), norm fp32. (unchanged)
// ---------------------------------------------------------------------------
__global__ __launch_bounds__(256, 4) void k3_out(
    const float* __restrict__ Q, const float* __restrict__ KVm,
    const float* __restrict__ ksum, float* __restrict__ out)
{
    __shared__ float cbuf[4][16 * 68];     // 17.4 KB, per-wave strips
    const int tid  = threadIdx.x;
    const int w    = tid >> 6;
    const int l    = tid & 63;
    const int r16  = l & 15;
    const int quad = l >> 4;
    const int bh    = blockIdx.x >> 4;
    const int strip = blockIdx.x & 15;     // 16 strips x 256 rows

    const float* kvp = KVm + (long)bh * 4096;
    short8 bfrag[2][4];
#pragma unroll
    for (int kh = 0; kh < 2; ++kh)
#pragma unroll
        for (int n = 0; n < 4; ++n) {
            short8 tmp;
#pragma unroll
            for (int j = 0; j < 8; ++j)
                tmp[j] = (short)f2bf(kvp[(kh * 32 + quad * 8 + j) * 64 + n * 16 + r16]);
            bfrag[kh][n] = tmp;
        }
    float ksv[16];
#pragma unroll
    for (int j = 0; j < 8; ++j) {
        ksv[j]     = ksum[bh * 64 + quad * 8 + j];
        ksv[j + 8] = ksum[bh * 64 + 32 + quad * 8 + j];
    }

    const int rowbase = strip * 256 + w * 64;
    const float* qptr = Q + ((long)bh * SDIM + rowbase + r16) * DDIM + quad * 8;
    float* obase = out + ((long)bh * SDIM + rowbase) * DDIM;
    float* cw = &cbuf[w][0];

    f32x4 a0 = *(const f32x4*)(qptr);
    f32x4 a1 = *(const f32x4*)(qptr + 4);
    f32x4 a2 = *(const f32x4*)(qptr + 32);
    f32x4 a3 = *(const f32x4*)(qptr + 36);

    for (int t = 0; t < 4; ++t) {
        f32x4 b0 = a0, b1 = a1, b2 = a2, b3 = a3;
        if (t < 3) {
            const float* qn = qptr + (t + 1) * 16 * DDIM;
            b0 = *(const f32x4*)(qn);
            b1 = *(const f32x4*)(qn + 4);
            b2 = *(const f32x4*)(qn + 32);
            b3 = *(const f32x4*)(qn + 36);
        }
#pragma unroll
        for (int j = 0; j < 4; ++j) {
            a0[j] = fmaxf(a0[j], 0.f); a1[j] = fmaxf(a1[j], 0.f);
            a2[j] = fmaxf(a2[j], 0.f); a3[j] = fmaxf(a3[j], 0.f);
        }
        float p = 0.f;
#pragma unroll
        for (int j = 0; j < 4; ++j) {
            p = fmaf(a0[j], ksv[j],      p);
            p = fmaf(a1[j], ksv[4 + j],  p);
            p = fmaf(a2[j], ksv[8 + j],  p);
            p = fmaf(a3[j], ksv[12 + j], p);
        }
        p += __shfl_xor(p, 16);
        p += __shfl_xor(p, 32);
        const float inv = __builtin_amdgcn_rcpf(p);

        short8 af0, af1;
#pragma unroll
        for (int j = 0; j < 4; ++j) {
            af0[j]     = (short)f2bf(a0[j]);
            af0[4 + j] = (short)f2bf(a1[j]);
            af1[j]     = (short)f2bf(a2[j]);
            af1[4 + j] = (short)f2bf(a3[j]);
        }

        f32x4 acc[4];
#pragma unroll
        for (int n = 0; n < 4; ++n) {
            acc[n] = (f32x4){0.f, 0.f, 0.f, 0.f};
            acc[n] = __builtin_amdgcn_mfma_f32_16x16x32_bf16(af0, bfrag[0][n], acc[n], 0, 0, 0);
            acc[n] = __builtin_amdgcn_mfma_f32_16x16x32_bf16(af1, bfrag[1][n], acc[n], 0, 0, 0);
        }

        float invr[4];
#pragma unroll
        for (int r = 0; r < 4; ++r) invr[r] = __shfl(inv, quad * 4 + r);

#pragma unroll
        for (int n = 0; n < 4; ++n)
#pragma unroll
            for (int r = 0; r < 4; ++r)
                cw[(quad * 4 + r) * 68 + n * 16 + r16] = acc[n][r] * invr[r];

        float* ot = obase + (t * 16) * DDIM;
#pragma unroll
        for (int i = 0; i < 4; ++i) {
            f32x4 v = *(const f32x4*)(cw + (i * 4 + quad) * 68 + r16 * 4);
            *(f32x4*)(ot + (i * 4 + quad) * DDIM + r16 * 4) = v;
        }
        a0 = b0; a1 = b1; a2 = b2; a3 = b3;
    }
}

extern "C" void kernel_launch(void* const* d_in, const int* in_sizes, int n_in,
                              void* d_out, int out_size, void* d_ws, size_t ws_size,
                              hipStream_t stream)
{
    const float* Q    = (const float*)d_in[0];
    const float* K    = (const float*)d_in[1];
    const float* V    = (const float*)d_in[2];
    const int*   mask = (const int*)d_in[3];
    float* out = (float*)d_out;

    // Chunk partials live in d_out (scratch; k3 overwrites all of d_out).
    float* KVp   = out;                                // 16.8 MB scratch
    float* ksump = KVp + (long)BH * NC * 4096;         // 256 KB
    float* KV    = (float*)d_ws;                       // 1 MB
    float* ksum  = KV + (long)BH * 4096;               // 16 KB

    hipLaunchKernelGGL(k1_kv, dim3(BH * NC), dim3(256), 0, stream,
                       K, V, mask, KVp, ksump);
    hipLaunchKernelGGL(k2_reduce, dim3(BH * 4), dim3(256), 0, stream,
                       KVp, ksump, KV, ksum);
    hipLaunchKernelGGL(k3_out, dim3(BH * 16), dim3(256), 0, stream,
                       Q, KV, ksum, out);
}